// Round 11
// baseline (1986.952 us; speedup 1.0000x reference)
//
// Persistent cooperative LSTM kernel for MI355X (gfx950) — round 19.
//  - R18 (128 blocks x 8 units) with the FC pass-2 lane-selection BUG FIXED.
//    R18 failed (absmax 2128): fc_write(.., cofs=4) wrote lanes col 0-3
//    (value = W1h@relu, full magnitude) into the Wskip slots; correct is
//    each lane writing ITS OWN column, restricted to [cofs, cofs+4) —
//    wfcf's output col 0-3 = W1h, col 4-7 = Wskip. ustate integrated the
//    wrong matmul over 31 autoregressive steps => blowup.
//  - Fix: fc_write guard (col & ~3) == cofs; lane stores its own a1/a2 at
//    its own column. fc_finish reads (cb_, cb_+4) unchanged.
//  - Rest is R18-verbatim (re-verified: mm chunk addressing, B/C column
//    maps, publish packing, zero-init, final pass, x-prefetch parity).
//  - Theory under test (R18's): 128 blocks x 8 units halves per-phase
//    exchange L2 reads (32 -> 16 MB) = the largest modeled interval term.
//  - absmax canary: exactly 0.0009765625. Revert if VGPR ~512 + FETCH/WRITE
//    inflation (spill).
#include <hip/hip_runtime.h>

typedef __attribute__((ext_vector_type(8))) short short8;
typedef __attribute__((ext_vector_type(4))) float float4_;
typedef __attribute__((ext_vector_type(4))) int int4_;
typedef unsigned long long u64;

#define AGENT __HIP_MEMORY_SCOPE_AGENT

// 226 regions x 131072 B: h0 g=-1..95 | h1 g=-1..95 | relu t=0..31
__device__ __attribute__((aligned(4096))) unsigned long long gws_static[3702784];

__device__ __forceinline__ unsigned short f2bf(float f) {
    unsigned u = __builtin_bit_cast(unsigned, f);
    u = (u + 0x7FFFu + ((u >> 16) & 1u)) >> 16;
    return (unsigned short)u;
}
__device__ __forceinline__ float bf2f(unsigned short h) {
    unsigned u = ((unsigned)h) << 16;
    return __builtin_bit_cast(float, u);
}
__device__ __forceinline__ float sigm(float x) { return 1.0f / (1.0f + __expf(-x)); }
__device__ __forceinline__ float tanhf_(float x) {
    x = fminf(fmaxf(x, -15.0f), 15.0f);
    float e = __expf(2.0f * x);
    return (e - 1.0f) / (e + 1.0f);
}

// coherent stores (write-through to coherence point)
__device__ __forceinline__ void st8_coh(unsigned short* p, unsigned long long v) {
    asm volatile("global_store_dwordx2 %0, %1, off sc0 sc1" :: "v"(p), "v"(v) : "memory");
}
__device__ __forceinline__ void st4_coh(unsigned short* p, unsigned v) {
    asm volatile("global_store_dword %0, %1, off sc0 sc1" :: "v"(p), "v"(v) : "memory");
}

// ---- symmetric all-poll grid barrier (128 blocks) ----
__device__ __forceinline__ void gbar_arrive(unsigned* flags, unsigned target, int blk) {
    asm volatile("s_waitcnt vmcnt(0)" ::: "memory");
    __syncthreads();
    if (threadIdx.x == 0)
        __hip_atomic_store(flags + blk * 16, target, __ATOMIC_RELAXED, AGENT);
}
__device__ __forceinline__ void gbar_wait(unsigned* flags, unsigned target) {
    if (threadIdx.x < 128) {
        while (__hip_atomic_load(flags + threadIdx.x * 16, __ATOMIC_RELAXED, AGENT) < target)
            __builtin_amdgcn_s_sleep(2);
    }
    __syncthreads();
}
__device__ __forceinline__ void gbar(unsigned* flags, unsigned target, int blk) {
    gbar_arrive(flags, target, blk);
    gbar_wait(flags, target);
}

__device__ __forceinline__ void zero4(float4_ (&a)[4]) {
    float4_ z;
    z[0] = 0.f; z[1] = 0.f; z[2] = 0.f; z[3] = 0.f;
#pragma unroll
    for (int i = 0; i < 4; i++) a[i] = z;
}

// ---- pipelined chunked staging, plain cached loads ----
#define LD4P(dst, base, OFF) \
    asm volatile("global_load_dwordx4 %0, %1, off offset:" #OFF \
                 : "=v"(dst) : "v"(base))

// 8 chunk-base pointers; chunk = q*32 + s*4 + (lane>>4); row m = lane&15.
#define BASES8(P, A) \
    const char* P##0 = (const char*)(A) + q * 32768 + (lane >> 4) * 1024 + (lane & 15) * 16; \
    const char* P##1 = P##0 + 4096;  const char* P##2 = P##0 + 8192; \
    const char* P##3 = P##0 + 12288; const char* P##4 = P##0 + 16384; \
    const char* P##5 = P##0 + 20480; const char* P##6 = P##0 + 24576; \
    const char* P##7 = P##0 + 28672;

// 8 loads = one batch-tile (mt): one dwordx4 (full A-frag) per s-block.
#define ISSUE8(F, P, OFF) \
    do { LD4P(F[0], P##0, OFF); LD4P(F[1], P##1, OFF); LD4P(F[2], P##2, OFF); \
         LD4P(F[3], P##3, OFF); LD4P(F[4], P##4, OFF); LD4P(F[5], P##5, OFF); \
         LD4P(F[6], P##6, OFF); LD4P(F[7], P##7, OFF); } while (0)

#define WAITV8(N, F) \
    asm volatile("s_waitcnt vmcnt(" #N ")" \
                 : "+v"(F[0]), "+v"(F[1]), "+v"(F[2]), "+v"(F[3]), \
                   "+v"(F[4]), "+v"(F[5]), "+v"(F[6]), "+v"(F[7]))

// Dual-B MFMA: the shared A-fragment feeds both unit-groups' accumulators.
#define MFMA8D(F, B1, B2, A1, A2) \
    do { _Pragma("unroll") \
         for (int s_ = 0; s_ < 8; s_++) { \
             short8 f_ = __builtin_bit_cast(short8, F[s_]); \
             A1 = __builtin_amdgcn_mfma_f32_16x16x32_bf16(f_, B1[s_], A1, 0, 0, 0); \
             A2 = __builtin_amdgcn_mfma_f32_16x16x32_bf16(f_, B2[s_], A2, 0, 0, 0); } } while (0)

// A chunked [128 chunks][64 b][8 u] bf16. A-frag: m = lane&15 (+16*mt),
// k = q*256 + (lane>>4)*8 + s*32 + j (chunk = k/8). One dwordx4 per frag.
// 2-deep rotating 8-load batches, partial vmcnt(8); ends WAITV8(0).
__device__ __forceinline__ void mm_pipe(const unsigned short* __restrict__ A,
                                        int q, int lane,
                                        const short8 (&b1)[8], const short8 (&b2)[8],
                                        float4_ (&a1)[4], float4_ (&a2)[4]) {
    BASES8(p_, A)
    int4_ fA[8], fB[8];
    ISSUE8(fA, p_, 0);
    ISSUE8(fB, p_, 256);
    WAITV8(8, fA); MFMA8D(fA, b1, b2, a1[0], a2[0]);
    ISSUE8(fA, p_, 512);
    WAITV8(8, fB); MFMA8D(fB, b1, b2, a1[1], a2[1]);
    ISSUE8(fB, p_, 768);
    WAITV8(8, fA); MFMA8D(fA, b1, b2, a1[2], a2[2]);
    WAITV8(0, fB); MFMA8D(fB, b1, b2, a1[3], a2[3]);
}

// gparts stride 33; group gr at cols gr*16+0..15.
__device__ __forceinline__ void write_parts(float* gp, int q, int lane,
                                            float4_ (&a1)[4], float4_ (&a2)[4]) {
    const int col = lane & 15;
    const int rbase = (lane >> 4) * 4;
#pragma unroll
    for (int mt = 0; mt < 4; mt++)
#pragma unroll
        for (int r = 0; r < 4; r++) {
            gp[(q * 64 + mt * 16 + rbase + r) * 33 + col] = a1[mt][r];
            gp[(q * 64 + mt * 16 + rbase + r) * 33 + 16 + col] = a2[mt][r];
        }
}

__device__ __forceinline__ float gsum(const float* gp, int b, int c) {
    return gp[(0 * 64 + b) * 33 + c] + gp[(1 * 64 + b) * 33 + c] +
           gp[(2 * 64 + b) * 33 + c] + gp[(3 * 64 + b) * 33 + c];
}

__device__ __forceinline__ short8 packrow(const float* __restrict__ p) {
    short8 r;
#pragma unroll
    for (int j = 0; j < 8; j++) r[j] = (short)f2bf(p[j]);
    return r;
}

__global__ void __launch_bounds__(256, 1)
lstm_core(const float* __restrict__ x, const float* __restrict__ lastp,
          const float* __restrict__ Wih0, const float* __restrict__ Whh0,
          const float* __restrict__ bih0, const float* __restrict__ bhh0,
          const float* __restrict__ Wih1, const float* __restrict__ Whh1,
          const float* __restrict__ bih1, const float* __restrict__ bhh1,
          const float* __restrict__ W1, const float* __restrict__ b1,
          const float* __restrict__ W2, const float* __restrict__ b2,
          float* __restrict__ out, unsigned char* __restrict__ wsb)
{
    const int tid = threadIdx.x;
    const int blk = blockIdx.x;      // 0..127
    const int lane = tid & 63;
    const int q = tid >> 6;          // wave id = K quarter
    const int eb = tid >> 2;         // epilogue: batch row
    const int eu = tid & 3;          // epilogue: unit-pair (units 2eu, 2eu+1)

    unsigned* bar   = (unsigned*)wsb;            // magic word only (bar+544)
    unsigned* flags = (unsigned*)(wsb + 8192);   // 128 flag words (64B spread)
    unsigned short* h0base = (unsigned short*)gws_static;
    unsigned short* h1base = h0base + (size_t)97 * 65536;
    unsigned short* relub  = h0base + (size_t)194 * 65536;

    auto h0p = [&](int g) -> unsigned short* {
        return h0base + (size_t)(g + 1) * 65536;
    };
    auto h1p = [&](int g) -> unsigned short* {
        return h1base + (size_t)(g + 1) * 65536;
    };

    __shared__ float gparts[4 * 64 * 33];
    __shared__ float xlds[2][64 * 21];
    __shared__ float wih0l[32 * 20];

    // ---- barrier area init (block 0): zero flags, then magic ----
    if (blk == 0) {
        if (tid < 128)
            __hip_atomic_store(flags + tid * 16, 0u, __ATOMIC_RELAXED, AGENT);
        __syncthreads();
        if (tid == 0)
            __hip_atomic_store(bar + 544, 0x1357BDFu, __ATOMIC_RELEASE, AGENT);
    }

    // ---- prologue: stage x[0] into xlds[0] ----
    for (int i = tid; i < 1280; i += 256) {
        const int bb = i / 20, mm = i - bb * 20;
        xlds[0][bb * 21 + mm] = x[bb * 1280 + mm];
    }

    // ---- per-lane B-fragment preload: 2 unit-groups x 5 sets ----
    const int n_ = lane & 15;
    const int gq_ = n_ >> 2, uu_ = n_ & 3;
    const int kq = (q << 8) + ((lane >> 4) << 3);

    short8 whh0f[2][8], wih1f[2][8], whh1f[2][8], wfusedf[2][8], wfcf[2][8];
#pragma unroll
    for (int gr = 0; gr < 2; gr++) {
        const int growL = gq_ * 1024 + blk * 8 + gr * 4 + uu_;
#pragma unroll
        for (int s = 0; s < 8; s++) {
            const int k = kq + s * 32;
            whh0f[gr][s] = packrow(Whh0 + growL * 1024 + k);
            wih1f[gr][s] = packrow(Wih1 + growL * 1024 + k);
            whh1f[gr][s] = packrow(Whh1 + growL * 1024 + k);
            { // Wfused[row][k] = sum_m Wih0[row][m] * W2[m][k]
                float a8[8] = {0.f, 0.f, 0.f, 0.f, 0.f, 0.f, 0.f, 0.f};
                for (int m = 0; m < 20; m++) {
                    float wv = Wih0[growL * 20 + m];
                    const float* w2p = W2 + m * 1024 + k;
#pragma unroll
                    for (int j = 0; j < 8; j++) a8[j] += wv * w2p[j];
                }
                short8 r;
#pragma unroll
                for (int j = 0; j < 8; j++) r[j] = (short)f2bf(a8[j]);
                wfusedf[gr][s] = r;
            }
            { // fc B: cols 0-3 = W1h rows, 4-7 = Wskip rows, 8-15 = 0
                short8 r;
                if (n_ < 4) {
                    r = packrow(W1 + (blk * 8 + gr * 4 + n_) * 1040 + k);
                } else if (n_ < 8) {
                    const int D = blk * 8 + gr * 4 + (n_ - 4);
                    float a8[8] = {0.f, 0.f, 0.f, 0.f, 0.f, 0.f, 0.f, 0.f};
                    for (int g2 = 0; g2 < 16; g2++) {
                        const int m = 5 * (g2 >> 2) + (g2 & 3);
                        float wv = W1[D * 1040 + 1024 + g2] * 0.01f;
                        const float* w2p = W2 + m * 1024 + k;
#pragma unroll
                        for (int j = 0; j < 8; j++) a8[j] += wv * w2p[j];
                    }
#pragma unroll
                    for (int j = 0; j < 8; j++) r[j] = (short)f2bf(a8[j]);
                } else {
#pragma unroll
                    for (int j = 0; j < 8; j++) r[j] = 0;
                }
                wfcf[gr][s] = r;
            }
        }
    }

    // ---- per-thread constants for units u_i = 2*eu + i ----
    float bias0g[2][4], bias1g[2][4], cgv[2][4];
    float fcb[2], cbv[2], ustate[2], c0v[2], c1v[2];
#pragma unroll
    for (int ui = 0; ui < 2; ui++) {
        const int D_ = blk * 8 + 2 * eu + ui;
#pragma unroll
        for (int g = 0; g < 4; g++) {
            const int row = g * 1024 + D_;
            bias0g[ui][g] = bih0[row] + bhh0[row];
            bias1g[ui][g] = bih1[row] + bhh1[row];
            float s = 0.f;
            for (int m = 0; m < 20; m++) s += Wih0[row * 20 + m] * b2[m];
            cgv[ui][g] = s;
        }
        fcb[ui] = b1[D_];
        float cb = 0.f, us = 0.f;
        for (int g2 = 0; g2 < 16; g2++) {
            const float w1v = W1[D_ * 1040 + 1024 + g2];
            cb += b2[5 * (g2 >> 2) + (g2 & 3)] * w1v * 0.01f;
            us += lastp[eb * 16 + g2] * w1v;
        }
        cbv[ui] = cb;
        ustate[ui] = us;
        c0v[ui] = 0.f;
        c1v[ui] = 0.f;
    }

    if (tid < 32) { // Wih0 rows for x-path: row = gate*8 + unit
        const int row = (tid >> 3) * 1024 + blk * 8 + (tid & 7);
        for (int m = 0; m < 20; m++) wih0l[tid * 20 + m] = Wih0[row * 20 + m];
    }
    // zero initial h state (g = -1): block's 1 KB chunk
    if (tid < 128) {
        st8_coh(h0p(-1) + blk * 512 + tid * 4, 0ull);
        st8_coh(h1p(-1) + blk * 512 + tid * 4, 0ull);
    }

    if (tid == 0) {
        while (__hip_atomic_load(bar + 544, __ATOMIC_RELAXED, AGENT) != 0x1357BDFu)
            __builtin_amdgcn_s_sleep(2);
    }
    __syncthreads();
    unsigned tgt = 1;
    gbar(flags, tgt, blk); tgt++;

    // ---- publish: thread packs units (2eu, 2eu+1) of batch eb: one dword ----
    auto publish = [&](unsigned short* dst, unsigned short v0, unsigned short v1) {
        st4_coh(dst + blk * 512 + eb * 8 + eu * 2,
                (unsigned)v0 | ((unsigned)v1 << 16));
    };

    auto l0_finish = [&](float4_ (&a1)[4], float4_ (&a2)[4],
                         unsigned short* h0dst, int xt, int pf) {
        write_parts(gparts, q, lane, a1, a2);
        __syncthreads();
        if (pf >= 0) {
            for (int i = tid; i < 1280; i += 256) {
                const int bb = i / 20, mm = i - bb * 20;
                xlds[pf & 1][bb * 21 + mm] = x[bb * 1280 + pf * 20 + mm];
            }
        }
        unsigned short hv[2];
#pragma unroll
        for (int ui = 0; ui < 2; ui++) {
            const int u = 2 * eu + ui;
            const int cb_ = (u >> 2) * 16 + (u & 3);
            float gv[4];
#pragma unroll
            for (int g = 0; g < 4; g++) gv[g] = gsum(gparts, eb, cb_ + g * 4) + bias0g[ui][g];
            if (xt >= 0) {
#pragma unroll
                for (int g = 0; g < 4; g++) {
                    float s = 0.f;
                    const float* wr = &wih0l[(g * 8 + u) * 20];
                    const float* xr = &xlds[xt & 1][eb * 21];
                    for (int m = 0; m < 20; m++) s += xr[m] * wr[m];
                    gv[g] += s;
                }
            } else {
#pragma unroll
                for (int g = 0; g < 4; g++) gv[g] += cgv[ui][g];
            }
            const float iv = sigm(gv[0]), fv = sigm(gv[1]);
            const float gt = tanhf_(gv[2]), ov = sigm(gv[3]);
            c0v[ui] = fv * c0v[ui] + iv * gt;
            hv[ui] = f2bf(ov * tanhf_(c0v[ui]));
        }
        publish(h0dst, hv[0], hv[1]);
    };

    auto l1_finish = [&](float4_ (&a1)[4], float4_ (&a2)[4], unsigned short* h1dst) {
        write_parts(gparts, q, lane, a1, a2);
        __syncthreads();
        unsigned short hv[2];
#pragma unroll
        for (int ui = 0; ui < 2; ui++) {
            const int u = 2 * eu + ui;
            const int cb_ = (u >> 2) * 16 + (u & 3);
            float gv[4];
#pragma unroll
            for (int g = 0; g < 4; g++) gv[g] = gsum(gparts, eb, cb_ + g * 4) + bias1g[ui][g];
            const float iv = sigm(gv[0]), fv = sigm(gv[1]);
            const float gt = tanhf_(gv[2]), ov = sigm(gv[3]);
            c1v[ui] = fv * c1v[ui] + iv * gt;
            hv[ui] = f2bf(ov * tanhf_(c1v[ui]));
        }
        publish(h1dst, hv[0], hv[1]);
    };

    // FC write pass: each lane writes ITS OWN column, restricted to the
    // 4-column window [cofs, cofs+4) that this pass's B data occupies.
    // (R18 bug: pass 2 wrote lanes 0-3 — whose value is W1h@relu — into the
    // Wskip slots. Lane col 4-7 holds the actual Wskip dot product.)
    auto fc_write = [&](float4_ (&a1)[4], float4_ (&a2)[4], int cofs) {
        const int col = lane & 15;
        const int rbase = (lane >> 4) * 4;
        if ((col & ~3) == cofs) {
#pragma unroll
            for (int mt = 0; mt < 4; mt++)
#pragma unroll
                for (int r = 0; r < 4; r++) {
                    gparts[(q * 64 + mt * 16 + rbase + r) * 33 + col] = a1[mt][r];
                    gparts[(q * 64 + mt * 16 + rbase + r) * 33 + 16 + col] = a2[mt][r];
                }
        }
    };

    auto fc_finish = [&](int t) {
        __syncthreads();
        unsigned short rv2[2];
#pragma unroll
        for (int ui = 0; ui < 2; ui++) {
            const int u = 2 * eu + ui;
            const int cb_ = (u >> 2) * 16 + (u & 3);
            const float s1 = gsum(gparts, eb, cb_);
            if (t > 0) ustate[ui] += gsum(gparts, eb, cb_ + 4) + cbv[ui];
            rv2[ui] = f2bf(fmaxf(s1 + ustate[ui] + fcb[ui], 0.f));
        }
        publish(relub + t * 65536, rv2[0], rv2[1]);
    };

    // ---- encoder: 64 steps x {L0, barrier, L1} ----
    for (int g = 0; g < 64; g++) {
        float4_ a1[4], a2[4];
        zero4(a1); zero4(a2);
        mm_pipe(h0p(g - 1), q, lane, whh0f[0], whh0f[1], a1, a2);
        l0_finish(a1, a2, h0p(g), g, (g < 63) ? g + 1 : -1);
        gbar(flags, tgt, blk); tgt++;
        zero4(a1); zero4(a2);
        mm_pipe(h0p(g), q, lane, wih1f[0], wih1f[1], a1, a2);
        mm_pipe(h1p(g - 1), q, lane, whh1f[0], whh1f[1], a1, a2);
        l1_finish(a1, a2, h1p(g));
    }

    // ---- decoder: 32 steps x {L0, b, L1, b, FC, b} ----
    for (int t = 0; t < 32; t++) {
        const int g = 64 + t;
        unsigned short* rp = (t > 0) ? (relub + (t - 1) * 65536) : nullptr;

        float4_ a1[4], a2[4];
        zero4(a1); zero4(a2);
        mm_pipe(h0p(g - 1), q, lane, whh0f[0], whh0f[1], a1, a2);
        if (rp) mm_pipe(rp, q, lane, wfusedf[0], wfusedf[1], a1, a2); // whh0 then wfused
        l0_finish(a1, a2, h0p(g), (t == 0) ? 63 : -1, -1);
        gbar(flags, tgt, blk); tgt++;

        zero4(a1); zero4(a2);
        mm_pipe(h0p(g), q, lane, wih1f[0], wih1f[1], a1, a2);
        mm_pipe(h1p(g - 1), q, lane, whh1f[0], whh1f[1], a1, a2);
        l1_finish(a1, a2, h1p(g));
        gbar(flags, tgt, blk); tgt++;

        // FC: pass 1 = W1h@h1 (cols 0-3); pass 2 = Wskip@relu (cols 4-7)
        zero4(a1); zero4(a2);
        mm_pipe(h1p(g), q, lane, wfcf[0], wfcf[1], a1, a2);
        fc_write(a1, a2, 0);
        if (rp) {
            zero4(a1); zero4(a2);
            mm_pipe(rp, q, lane, wfcf[0], wfcf[1], a1, a2);
            fc_write(a1, a2, 4);
        }
        fc_finish(t);
        gbar(flags, tgt, blk); tgt++;
    }

    // ---- final: pred[t] = relu[t] @ W2^T + b2 -> out[b][t][m] ----
    for (int it = 0; it < 2; it++) {
        const int pj = tid >> 5;   // 8 pairs per sub-round
        const int m = tid & 31;
        if (m < 20) {
            const int pidx = blk * 16 + it * 8 + pj;
            const int tt = pidx >> 6, bb = pidx & 63;
            const unsigned short* rr = relub + tt * 65536;  // [128ch][64b][8u]
            const float* w = W2 + m * 1024;
            float acc = 0.f;
            for (int c = 0; c < 128; c++) {
                const u64 v0 = *(const u64*)(rr + c * 512 + bb * 8);
                const u64 v1 = *(const u64*)(rr + c * 512 + bb * 8 + 4);
#pragma unroll
                for (int j = 0; j < 4; j++) {
                    acc += bf2f((unsigned short)(v0 >> (16 * j))) * w[c * 8 + j];
                    acc += bf2f((unsigned short)(v1 >> (16 * j))) * w[c * 8 + 4 + j];
                }
            }
            out[bb * 640 + tt * 20 + m] = acc + b2[m];
        }
    }
}

extern "C" void kernel_launch(void* const* d_in, const int* in_sizes, int n_in,
                              void* d_out, int out_size, void* d_ws, size_t ws_size,
                              hipStream_t stream) {
    (void)in_sizes; (void)n_in; (void)out_size; (void)ws_size;
    const float* x     = (const float*)d_in[0];
    const float* lastp = (const float*)d_in[1];
    const float* Wih0  = (const float*)d_in[2];
    const float* Whh0  = (const float*)d_in[3];
    const float* bih0  = (const float*)d_in[4];
    const float* bhh0  = (const float*)d_in[5];
    const float* Wih1  = (const float*)d_in[6];
    const float* Whh1  = (const float*)d_in[7];
    const float* bih1  = (const float*)d_in[8];
    const float* bhh1  = (const float*)d_in[9];
    const float* W1    = (const float*)d_in[10];
    const float* b1    = (const float*)d_in[11];
    const float* W2    = (const float*)d_in[12];
    const float* b2    = (const float*)d_in[13];
    float* out = (float*)d_out;
    unsigned char* ws = (unsigned char*)d_ws;

    void* args[] = {&x, &lastp, &Wih0, &Whh0, &bih0, &bhh0, &Wih1, &Whh1,
                    &bih1, &bhh1, &W1, &b1, &W2, &b2, &out, &ws};
    hipError_t err = hipLaunchCooperativeKernel((const void*)lstm_core,
                                                dim3(128), dim3(256), args, 0, stream);
    if (err != hipSuccess) {
        hipLaunchKernelGGL(lstm_core, dim3(128), dim3(256), 0, stream,
                           x, lastp, Wih0, Whh0, bih0, bhh0, Wih1, Whh1,
                           bih1, bhh1, W1, b1, W2, b2, out, ws);
    }
}

// Round 12
// 1245.689 us; speedup vs baseline: 1.5951x; 1.5951x over previous
//
// Persistent cooperative LSTM kernel for MI355X (gfx950) — round 20.
//  - R19 post-mortem: 128-block/8-unit spilled (FETCH/WRITE 504/463 MB of
//    scratch traffic) => shelved. REVERT to R17 structure (best, ~1363).
//  - NEW: dual-B mm merge — same read-amplification attack, zero extra
//    persistent registers. Phases that read the SAME A-matrix with two
//    different weight sets are fused into ONE 128 KB read feeding two
//    MFMA accumulators (R18's dual-B, whose only bug was FC lane select):
//      * encoder L1: mm_d(h0(g), wih1->accL1, whh0->haccL0 for next L0);
//        L0 slot becomes epilogue-only (haccL0 carried in registers).
//        g=0: whh0@h0(-1) == 0 exactly -> haccL0 init = zero4.
//      * decoder L1: same dual (replaces the FC-wait whh0 hoist).
//      * decoder L0: mm_d(relu, wfused->acc, wfc/Wskip->haccSkip)
//        (replaces the L0-wait Wskip hoist).
//    mm passes 384 -> 256 (-33% exchange L2 reads); encoder interval loses
//    one serial mm phase. Per-accumulator accumulation order UNCHANGED =>
//    bit-exact; absmax canary 0.0009765625.
//  - Barrier, publish, rotation, epilogues, x-prefetch: R17-verbatim.
//  - Revert criteria: FETCH/WRITE inflation (spill).
#include <hip/hip_runtime.h>

typedef __attribute__((ext_vector_type(8))) short short8;
typedef __attribute__((ext_vector_type(4))) float float4_;
typedef unsigned long long u64;
typedef __attribute__((ext_vector_type(2))) unsigned long long u64x2;

#define AGENT __HIP_MEMORY_SCOPE_AGENT

// 226 regions x 131072 B: h0 g=-1..95 | h1 g=-1..95 | relu t=0..31
__device__ __attribute__((aligned(4096))) unsigned long long gws_static[3702784];

__device__ __forceinline__ unsigned short f2bf(float f) {
    unsigned u = __builtin_bit_cast(unsigned, f);
    u = (u + 0x7FFFu + ((u >> 16) & 1u)) >> 16;
    return (unsigned short)u;
}
__device__ __forceinline__ float bf2f(unsigned short h) {
    unsigned u = ((unsigned)h) << 16;
    return __builtin_bit_cast(float, u);
}
__device__ __forceinline__ float sigm(float x) { return 1.0f / (1.0f + __expf(-x)); }
__device__ __forceinline__ float tanhf_(float x) {
    x = fminf(fmaxf(x, -15.0f), 15.0f);
    float e = __expf(2.0f * x);
    return (e - 1.0f) / (e + 1.0f);
}

// coherent stores (write-through to coherence point)
__device__ __forceinline__ void st8_coh(unsigned short* p, unsigned long long v) {
    asm volatile("global_store_dwordx2 %0, %1, off sc0 sc1" :: "v"(p), "v"(v) : "memory");
}
__device__ __forceinline__ void st2_coh(unsigned short* p, unsigned short v) {
    asm volatile("global_store_short %0, %1, off sc0 sc1" :: "v"(p), "v"((unsigned)v) : "memory");
}

// ---- symmetric all-poll grid barrier (R17-verbatim) ----
__device__ __forceinline__ void gbar_arrive(unsigned* flags, unsigned target, int blk) {
    asm volatile("s_waitcnt vmcnt(0)" ::: "memory");
    __syncthreads();
    if (threadIdx.x == 0)
        __hip_atomic_store(flags + blk * 16, target, __ATOMIC_RELAXED, AGENT);
}
__device__ __forceinline__ void gbar_wait(unsigned* flags, unsigned target) {
    while (__hip_atomic_load(flags + threadIdx.x * 16, __ATOMIC_RELAXED, AGENT) < target)
        __builtin_amdgcn_s_sleep(2);
    __syncthreads();
}
__device__ __forceinline__ void gbar(unsigned* flags, unsigned target, int blk) {
    gbar_arrive(flags, target, blk);
    gbar_wait(flags, target);
}

__device__ __forceinline__ void zero4(float4_ (&a)[4]) {
    float4_ z;
    z[0] = 0.f; z[1] = 0.f; z[2] = 0.f; z[3] = 0.f;
#pragma unroll
    for (int i = 0; i < 4; i++) a[i] = z;
}
__device__ __forceinline__ void copy4(float4_ (&d)[4], const float4_ (&s)[4]) {
#pragma unroll
    for (int i = 0; i < 4; i++) d[i] = s[i];
}

// ---- pipelined chunked staging, plain cached loads ----
#define LD2P(dst, base, OFF) \
    asm volatile("global_load_dwordx2 %0, %1, off offset:" #OFF \
                 : "=v"(dst) : "v"(base))

// 8 chunk-base pointers for one A matrix (chunked [256ch][64b][4u] bf16)
#define BASES8(P, A) \
    const char* P##0 = (const char*)(A) + q * 32768 + (lane >> 4) * 1024 + (lane & 15) * 8; \
    const char* P##1 = P##0 + 4096;  const char* P##2 = P##0 + 8192; \
    const char* P##3 = P##0 + 12288; const char* P##4 = P##0 + 16384; \
    const char* P##5 = P##0 + 20480; const char* P##6 = P##0 + 24576; \
    const char* P##7 = P##0 + 28672;

// 16 loads = one batch-tile (mt): 8 s-blocks x {lo,hi} chunk halves.
#define ISSUE16P(LO, HI, LD, P, O0, O1) \
    do { LD(LO[0], P##0, O0); LD(LO[1], P##1, O0); LD(LO[2], P##2, O0); \
         LD(LO[3], P##3, O0); LD(LO[4], P##4, O0); LD(LO[5], P##5, O0); \
         LD(LO[6], P##6, O0); LD(LO[7], P##7, O0); \
         LD(HI[0], P##0, O1); LD(HI[1], P##1, O1); LD(HI[2], P##2, O1); \
         LD(HI[3], P##3, O1); LD(HI[4], P##4, O1); LD(HI[5], P##5, O1); \
         LD(HI[6], P##6, O1); LD(HI[7], P##7, O1); } while (0)

#define WAITV16(N, LO, HI) \
    asm volatile("s_waitcnt vmcnt(" #N ")" \
                 : "+v"(LO[0]), "+v"(LO[1]), "+v"(LO[2]), "+v"(LO[3]), \
                   "+v"(LO[4]), "+v"(LO[5]), "+v"(LO[6]), "+v"(LO[7]), \
                   "+v"(HI[0]), "+v"(HI[1]), "+v"(HI[2]), "+v"(HI[3]), \
                   "+v"(HI[4]), "+v"(HI[5]), "+v"(HI[6]), "+v"(HI[7]))

#define MFMA8C(LO, HI, BF, ACCI) \
    do { _Pragma("unroll") \
         for (int s_ = 0; s_ < 8; s_++) { \
             u64x2 t_; t_[0] = LO[s_]; t_[1] = HI[s_]; \
             ACCI = __builtin_amdgcn_mfma_f32_16x16x32_bf16( \
                 __builtin_bit_cast(short8, t_), BF[s_], ACCI, 0, 0, 0); } } while (0)

// Dual-B: the shared A-fragment feeds two accumulators (separate outputs).
#define MFMA8C2(LO, HI, B1, B2, A1, A2) \
    do { _Pragma("unroll") \
         for (int s_ = 0; s_ < 8; s_++) { \
             u64x2 t_; t_[0] = LO[s_]; t_[1] = HI[s_]; \
             short8 f_ = __builtin_bit_cast(short8, t_); \
             A1 = __builtin_amdgcn_mfma_f32_16x16x32_bf16(f_, B1[s_], A1, 0, 0, 0); \
             A2 = __builtin_amdgcn_mfma_f32_16x16x32_bf16(f_, B2[s_], A2, 0, 0, 0); } } while (0)

// A chunked [256 chunks][64 b][4 u] bf16. A-frag: m = lane&15 (+16*mt),
// k = q*256 + (lane>>4)*8 + s*32 + j. Chunk pair for (s): bases[s], +512.
// 2-deep rotating 16-load batches, partial vmcnt(16); ends WAITV16(0).
__device__ __forceinline__ void mm_pipe(const unsigned short* __restrict__ A,
                                        int q, int lane,
                                        const short8 (&bf)[8], float4_ (&acc)[4]) {
    BASES8(p_, A)
    u64 loA[8], hiA[8], loB[8], hiB[8];
    ISSUE16P(loA, hiA, LD2P, p_, 0, 512);
    ISSUE16P(loB, hiB, LD2P, p_, 128, 640);
    WAITV16(16, loA, hiA); MFMA8C(loA, hiA, bf, acc[0]);
    ISSUE16P(loA, hiA, LD2P, p_, 256, 768);
    WAITV16(16, loB, hiB); MFMA8C(loB, hiB, bf, acc[1]);
    ISSUE16P(loB, hiB, LD2P, p_, 384, 896);
    WAITV16(16, loA, hiA); MFMA8C(loA, hiA, bf, acc[2]);
    WAITV16(0, loB, hiB);  MFMA8C(loB, hiB, bf, acc[3]);
}

// Dual-B variant: one A read, two B sets, two accumulator sets.
__device__ __forceinline__ void mm_pipe_d(const unsigned short* __restrict__ A,
                                          int q, int lane,
                                          const short8 (&b1)[8], const short8 (&b2)[8],
                                          float4_ (&a1)[4], float4_ (&a2)[4]) {
    BASES8(p_, A)
    u64 loA[8], hiA[8], loB[8], hiB[8];
    ISSUE16P(loA, hiA, LD2P, p_, 0, 512);
    ISSUE16P(loB, hiB, LD2P, p_, 128, 640);
    WAITV16(16, loA, hiA); MFMA8C2(loA, hiA, b1, b2, a1[0], a2[0]);
    ISSUE16P(loA, hiA, LD2P, p_, 256, 768);
    WAITV16(16, loB, hiB); MFMA8C2(loB, hiB, b1, b2, a1[1], a2[1]);
    ISSUE16P(loB, hiB, LD2P, p_, 384, 896);
    WAITV16(16, loA, hiA); MFMA8C2(loA, hiA, b1, b2, a1[2], a2[2]);
    WAITV16(0, loB, hiB);  MFMA8C2(loB, hiB, b1, b2, a1[3], a2[3]);
}

// C[m][n]: n = lane&15, m = quad*4+reg  -> gp[(q*64+row)*17+col]
__device__ __forceinline__ void write_parts(float* gp, int q, int lane, float4_ (&acc)[4]) {
    const int col = lane & 15;
    const int rbase = (lane >> 4) * 4;
#pragma unroll
    for (int mt = 0; mt < 4; mt++)
#pragma unroll
        for (int r = 0; r < 4; r++)
            gp[(q * 64 + mt * 16 + rbase + r) * 17 + col] = acc[mt][r];
}

__device__ __forceinline__ float gsum(const float* gp, int b, int c) {
    return gp[(0 * 64 + b) * 17 + c] + gp[(1 * 64 + b) * 17 + c] +
           gp[(2 * 64 + b) * 17 + c] + gp[(3 * 64 + b) * 17 + c];
}

__device__ __forceinline__ short8 packrow(const float* __restrict__ p) {
    short8 r;
#pragma unroll
    for (int j = 0; j < 8; j++) r[j] = (short)f2bf(p[j]);
    return r;
}

__global__ void __launch_bounds__(256, 1)
lstm_core(const float* __restrict__ x, const float* __restrict__ lastp,
          const float* __restrict__ Wih0, const float* __restrict__ Whh0,
          const float* __restrict__ bih0, const float* __restrict__ bhh0,
          const float* __restrict__ Wih1, const float* __restrict__ Whh1,
          const float* __restrict__ bih1, const float* __restrict__ bhh1,
          const float* __restrict__ W1, const float* __restrict__ b1,
          const float* __restrict__ W2, const float* __restrict__ b2,
          float* __restrict__ out, unsigned char* __restrict__ wsb)
{
    const int tid = threadIdx.x;
    const int blk = blockIdx.x;
    const int lane = tid & 63;
    const int q = tid >> 6;          // wave id = K quarter
    const int eb = tid >> 2;         // epilogue: batch row
    const int eu = tid & 3;          // epilogue: unit-within-block
    const int D_ = blk * 4 + eu;     // global hidden unit / fc dim

    unsigned* bar   = (unsigned*)wsb;            // magic word only (bar+544)
    unsigned* flags = (unsigned*)(wsb + 8192);   // 256 flag words (64B spread)
    unsigned short* h0base = (unsigned short*)gws_static;
    unsigned short* h1base = h0base + (size_t)97 * 65536;
    unsigned short* relub  = h0base + (size_t)194 * 65536;

    auto h0p = [&](int g) -> unsigned short* {
        return h0base + (size_t)(g + 1) * 65536;
    };
    auto h1p = [&](int g) -> unsigned short* {
        return h1base + (size_t)(g + 1) * 65536;
    };

    __shared__ float gparts[4 * 64 * 17];
    __shared__ float xlds[2][64 * 21];
    __shared__ float wih0l[16 * 20];

    // ---- barrier area init (block 0): zero flags, then magic ----
    if (blk == 0) {
        __hip_atomic_store(flags + tid * 16, 0u, __ATOMIC_RELAXED, AGENT);
        __syncthreads();
        if (tid == 0)
            __hip_atomic_store(bar + 544, 0x1357BDFu, __ATOMIC_RELEASE, AGENT);
    }

    // ---- prologue: stage x[0] into xlds[0] ----
    for (int i = tid; i < 1280; i += 256) {
        const int bb = i / 20, mm = i - bb * 20;
        xlds[0][bb * 21 + mm] = x[bb * 1280 + mm];
    }

    // ---- per-lane B-fragment preload (bf16, RNE) ----
    const int n_ = lane & 15;
    const int gq_ = n_ >> 2, uu_ = n_ & 3;
    const int growL = gq_ * 1024 + blk * 4 + uu_;   // gate row for this col
    const int kq = (q << 8) + ((lane >> 4) << 3);

    short8 whh0f[8], wih1f[8], whh1f[8], wfusedf[8], wfcf[8];
#pragma unroll
    for (int s = 0; s < 8; s++) {
        const int k = kq + s * 32;
        whh0f[s] = packrow(Whh0 + growL * 1024 + k);
        wih1f[s] = packrow(Wih1 + growL * 1024 + k);
        whh1f[s] = packrow(Whh1 + growL * 1024 + k);
        { // Wfused[row][k] = sum_m Wih0[row][m] * W2[m][k]
            float a8[8] = {0.f, 0.f, 0.f, 0.f, 0.f, 0.f, 0.f, 0.f};
            for (int m = 0; m < 20; m++) {
                float wv = Wih0[growL * 20 + m];
                const float* w2p = W2 + m * 1024 + k;
#pragma unroll
                for (int j = 0; j < 8; j++) a8[j] += wv * w2p[j];
            }
            short8 r;
#pragma unroll
            for (int j = 0; j < 8; j++) r[j] = (short)f2bf(a8[j]);
            wfusedf[s] = r;
        }
        { // fc B: cols 0-3 = W1h rows, cols 4-7 = Wskip rows, 8-15 = 0
            short8 r;
            if (n_ < 4) {
                r = packrow(W1 + (blk * 4 + n_) * 1040 + k);
            } else if (n_ < 8) {
                const int D = blk * 4 + (n_ - 4);
                float a8[8] = {0.f, 0.f, 0.f, 0.f, 0.f, 0.f, 0.f, 0.f};
                for (int g2 = 0; g2 < 16; g2++) {
                    const int m = 5 * (g2 >> 2) + (g2 & 3);
                    float wv = W1[D * 1040 + 1024 + g2] * 0.01f;
                    const float* w2p = W2 + m * 1024 + k;
#pragma unroll
                    for (int j = 0; j < 8; j++) a8[j] += wv * w2p[j];
                }
#pragma unroll
                for (int j = 0; j < 8; j++) r[j] = (short)f2bf(a8[j]);
            } else {
#pragma unroll
                for (int j = 0; j < 8; j++) r[j] = 0;
            }
            wfcf[s] = r;
        }
    }

    // ---- per-thread constants (epilogue mapping: eb = tid>>2, eu = tid&3) ----
    float bias0g[4], bias1g[4], cgv[4];
#pragma unroll
    for (int g = 0; g < 4; g++) {
        const int row = g * 1024 + D_;
        bias0g[g] = bih0[row] + bhh0[row];
        bias1g[g] = bih1[row] + bhh1[row];
        float s = 0.f;
        for (int m = 0; m < 20; m++) s += Wih0[row * 20 + m] * b2[m];
        cgv[g] = s;
    }
    const float fcb = b1[D_];
    float cbv = 0.f, ustate = 0.f;
    for (int g2 = 0; g2 < 16; g2++) {
        const float w1v = W1[D_ * 1040 + 1024 + g2];
        cbv += b2[5 * (g2 >> 2) + (g2 & 3)] * w1v * 0.01f;
        ustate += lastp[eb * 16 + g2] * w1v;   // u(0) = lp0 @ W1lp^T
    }
    float c0v = 0.f, c1v = 0.f;

    if (tid < 16) { // Wih0 rows for x-path (fp32, exact)
        const int row = (tid >> 2) * 1024 + blk * 4 + (tid & 3);
        for (int m = 0; m < 20; m++) wih0l[tid * 20 + m] = Wih0[row * 20 + m];
    }
    // zero initial h state (g = -1); chunked: chunk blk, batch tid
    if (tid < 64) {
        st8_coh(h0p(-1) + blk * 256 + tid * 4, 0ull);
        st8_coh(h1p(-1) + blk * 256 + tid * 4, 0ull);
    }

    if (tid == 0) {
        while (__hip_atomic_load(bar + 544, __ATOMIC_RELAXED, AGENT) != 0x1357BDFu)
            __builtin_amdgcn_s_sleep(2);
    }
    __syncthreads();
    unsigned tgt = 1;
    gbar(flags, tgt, blk); tgt++;

    // ---- direct per-thread publish: thread's element = chunk blk, idx tid ----
    auto publish = [&](unsigned short* dst, unsigned short val) {
        st2_coh(dst + blk * 256 + tid, val);
    };

    auto l0_finish = [&](float4_ (&acc)[4], unsigned short* h0dst, int xt, int pf) {
        write_parts(gparts, q, lane, acc);
        __syncthreads();
        if (pf >= 0) {
            for (int i = tid; i < 1280; i += 256) {
                const int bb = i / 20, mm = i - bb * 20;
                xlds[pf & 1][bb * 21 + mm] = x[bb * 1280 + pf * 20 + mm];
            }
        }
        float gv[4];
#pragma unroll
        for (int g = 0; g < 4; g++) gv[g] = gsum(gparts, eb, g * 4 + eu) + bias0g[g];
        if (xt >= 0) {
#pragma unroll
            for (int g = 0; g < 4; g++) {
                float s = 0.f;
                const float* wr = &wih0l[(g * 4 + eu) * 20];
                const float* xr = &xlds[xt & 1][eb * 21];
                for (int m = 0; m < 20; m++) s += xr[m] * wr[m];
                gv[g] += s;
            }
        } else {
#pragma unroll
            for (int g = 0; g < 4; g++) gv[g] += cgv[g];
        }
        const float iv = sigm(gv[0]), fv = sigm(gv[1]);
        const float gt = tanhf_(gv[2]), ov = sigm(gv[3]);
        c0v = fv * c0v + iv * gt;
        publish(h0dst, f2bf(ov * tanhf_(c0v)));
    };

    auto l1_finish = [&](float4_ (&acc)[4], unsigned short* h1dst) {
        write_parts(gparts, q, lane, acc);
        __syncthreads();
        float gv[4];
#pragma unroll
        for (int g = 0; g < 4; g++) gv[g] = gsum(gparts, eb, g * 4 + eu) + bias1g[g];
        const float iv = sigm(gv[0]), fv = sigm(gv[1]);
        const float gt = tanhf_(gv[2]), ov = sigm(gv[3]);
        c1v = fv * c1v + iv * gt;
        publish(h1dst, f2bf(ov * tanhf_(c1v)));
    };

    auto fc_finish = [&](int t, float4_ (&acc1)[4], float4_ (&acc2)[4]) {
        const int col = lane & 15;
        const int rbase = (lane >> 4) * 4;
        if (col < 8) {
#pragma unroll
            for (int mt = 0; mt < 4; mt++)
#pragma unroll
                for (int r = 0; r < 4; r++) {
                    const float v = (col < 4) ? acc1[mt][r] : acc2[mt][r];
                    gparts[(q * 64 + mt * 16 + rbase + r) * 17 + col] = v;
                }
        }
        __syncthreads();
        const float s1 = gsum(gparts, eb, eu);
        if (t > 0) ustate += gsum(gparts, eb, 4 + eu) + cbv;
        const float rv = fmaxf(s1 + ustate + fcb, 0.f);
        publish(relub + t * 65536, f2bf(rv));
    };

    // carried accumulators
    float4_ haccL0[4];   // whh0 @ h0(g) for the NEXT L0 (computed in L1's dual)
    float4_ haccSkip[4]; // Wskip @ relu(t-1) for FC (computed in L0's dual)
    zero4(haccL0);       // whh0 @ h0(-1) == 0 exactly (zero initial state)

    // ---- encoder: 64 steps x {L0(epilogue-only), barrier, L1(dual+mm)} ----
    for (int g = 0; g < 64; g++) {
        float4_ acc[4];
        copy4(acc, haccL0);                       // whh0 @ h0(g-1)
        l0_finish(acc, h0p(g), g, (g < 63) ? g + 1 : -1);
        gbar(flags, tgt, blk); tgt++;
        float4_ accn[4];
        zero4(accn); zero4(haccL0);
        mm_pipe_d(h0p(g), q, lane, wih1f, whh0f, accn, haccL0); // one h0 read
        mm_pipe(h1p(g - 1), q, lane, whh1f, accn);              // order: wih1 then whh1 ✓
        l1_finish(accn, h1p(g));
    }

    // ---- decoder: 32 steps x {L0, b, L1, b, FC, b} ----
    for (int t = 0; t < 32; t++) {
        const int g = 64 + t;
        unsigned short* rp = (t > 0) ? (relub + (t - 1) * 65536) : nullptr;

        // L0 slot: acc = whh0@h0(g-1) (carried) + wfused@relu (dual with Wskip)
        float4_ acc[4];
        copy4(acc, haccL0);
        zero4(haccSkip);
        if (rp) mm_pipe_d(rp, q, lane, wfusedf, wfcf, acc, haccSkip); // whh0 then wfused ✓
        l0_finish(acc, h0p(g), (t == 0) ? 63 : -1, -1);
        gbar(flags, tgt, blk); tgt++;

        // L1 slot: dual read of h0(g) (wih1 + whh0-for-next-L0), then whh1
        float4_ accn[4];
        zero4(accn); zero4(haccL0);
        mm_pipe_d(h0p(g), q, lane, wih1f, whh0f, accn, haccL0);
        mm_pipe(h1p(g - 1), q, lane, whh1f, accn);
        l1_finish(accn, h1p(g));
        gbar(flags, tgt, blk); tgt++;

        // FC slot: acc1 = W1h@h1 (cols 0-3 valid); acc2 = carried Wskip@relu
        float4_ acc1[4];
        zero4(acc1);
        mm_pipe(h1p(g), q, lane, wfcf, acc1);
        fc_finish(t, acc1, haccSkip);
        gbar(flags, tgt, blk); tgt++;
    }

    // ---- final: pred[t] = relu[t] @ W2^T + b2 -> out[b][t][m] ----
    {
        const int pj = tid >> 5;   // 8 (t,b) pairs per block
        const int m = tid & 31;
        if (m < 20) {
            const int pidx = blk * 8 + pj;
            const int tt = pidx >> 6, bb = pidx & 63;
            const unsigned short* rr = relub + tt * 65536;  // chunked region
            const float* w = W2 + m * 1024;
            float acc = 0.f;
            for (int c = 0; c < 256; c++) {
                const u64 v8 = *(const u64*)(rr + c * 256 + bb * 4);
#pragma unroll
                for (int j = 0; j < 4; j++)
                    acc += bf2f((unsigned short)(v8 >> (16 * j))) * w[c * 4 + j];
            }
            out[bb * 640 + tt * 20 + m] = acc + b2[m];
        }
    }
}

extern "C" void kernel_launch(void* const* d_in, const int* in_sizes, int n_in,
                              void* d_out, int out_size, void* d_ws, size_t ws_size,
                              hipStream_t stream) {
    (void)in_sizes; (void)n_in; (void)out_size; (void)ws_size;
    const float* x     = (const float*)d_in[0];
    const float* lastp = (const float*)d_in[1];
    const float* Wih0  = (const float*)d_in[2];
    const float* Whh0  = (const float*)d_in[3];
    const float* bih0  = (const float*)d_in[4];
    const float* bhh0  = (const float*)d_in[5];
    const float* Wih1  = (const float*)d_in[6];
    const float* Whh1  = (const float*)d_in[7];
    const float* bih1  = (const float*)d_in[8];
    const float* bhh1  = (const float*)d_in[9];
    const float* W1    = (const float*)d_in[10];
    const float* b1    = (const float*)d_in[11];
    const float* W2    = (const float*)d_in[12];
    const float* b2    = (const float*)d_in[13];
    float* out = (float*)d_out;
    unsigned char* ws = (unsigned char*)d_ws;

    void* args[] = {&x, &lastp, &Wih0, &Whh0, &bih0, &bhh0, &Wih1, &Whh1,
                    &bih1, &bhh1, &W1, &b1, &W2, &b2, &out, &ws};
    hipError_t err = hipLaunchCooperativeKernel((const void*)lstm_core,
                                                dim3(256), dim3(256), args, 0, stream);
    if (err != hipSuccess) {
        hipLaunchKernelGGL(lstm_core, dim3(256), dim3(256), 0, stream,
                           x, lastp, Wih0, Whh0, bih0, bhh0, Wih1, Whh1,
                           bih1, bhh1, W1, b1, W2, b2, out, ws);
    }
}

// Round 13
// 1232.820 us; speedup vs baseline: 1.6117x; 1.0104x over previous
//
// Persistent cooperative LSTM kernel for MI355X (gfx950) — round 21.
//  - Base = R20 (dual-B merges, 1156 µs rocprof). R20 calibration: each
//    128KB exchange read ~1.6 µs; barrier+skew ~4.7 µs/interval co-dominant.
//  - NEW: decoder whh1@h1(g-1) moved into the L0bar fuzzy WINDOW
//    (arrive -> mm -> wait), R15-proven-safe operand age: h1(g-1) drained
//    at arrive(L1bar(t-1)), window reader passed wait(FCbar(t-1)) => all
//    publishers drained. Hides ~1.6 µs AND absorbs arrival skew at 32
//    barriers. t=0 special case (h1(63) is 0-barriers-old): whh1 runs
//    in-phase post-wait.
//  - Decoder L1 accumulation order now whh1-then-wih1 (uniform all t):
//    deliberate order change, absmax canary moves off 0.0009765625 —
//    must stay <= 2.675781e-3 (expect ~1e-3). Encoder order unchanged.
//  - Everything else R20-verbatim. Spill canary: FETCH/WRITE ~166/34 MB.
#include <hip/hip_runtime.h>

typedef __attribute__((ext_vector_type(8))) short short8;
typedef __attribute__((ext_vector_type(4))) float float4_;
typedef unsigned long long u64;
typedef __attribute__((ext_vector_type(2))) unsigned long long u64x2;

#define AGENT __HIP_MEMORY_SCOPE_AGENT

// 226 regions x 131072 B: h0 g=-1..95 | h1 g=-1..95 | relu t=0..31
__device__ __attribute__((aligned(4096))) unsigned long long gws_static[3702784];

__device__ __forceinline__ unsigned short f2bf(float f) {
    unsigned u = __builtin_bit_cast(unsigned, f);
    u = (u + 0x7FFFu + ((u >> 16) & 1u)) >> 16;
    return (unsigned short)u;
}
__device__ __forceinline__ float bf2f(unsigned short h) {
    unsigned u = ((unsigned)h) << 16;
    return __builtin_bit_cast(float, u);
}
__device__ __forceinline__ float sigm(float x) { return 1.0f / (1.0f + __expf(-x)); }
__device__ __forceinline__ float tanhf_(float x) {
    x = fminf(fmaxf(x, -15.0f), 15.0f);
    float e = __expf(2.0f * x);
    return (e - 1.0f) / (e + 1.0f);
}

// coherent stores (write-through to coherence point)
__device__ __forceinline__ void st8_coh(unsigned short* p, unsigned long long v) {
    asm volatile("global_store_dwordx2 %0, %1, off sc0 sc1" :: "v"(p), "v"(v) : "memory");
}
__device__ __forceinline__ void st2_coh(unsigned short* p, unsigned short v) {
    asm volatile("global_store_short %0, %1, off sc0 sc1" :: "v"(p), "v"((unsigned)v) : "memory");
}

// ---- symmetric all-poll grid barrier (R17-verbatim), arrive/wait split ----
__device__ __forceinline__ void gbar_arrive(unsigned* flags, unsigned target, int blk) {
    asm volatile("s_waitcnt vmcnt(0)" ::: "memory");
    __syncthreads();
    if (threadIdx.x == 0)
        __hip_atomic_store(flags + blk * 16, target, __ATOMIC_RELAXED, AGENT);
}
__device__ __forceinline__ void gbar_wait(unsigned* flags, unsigned target) {
    while (__hip_atomic_load(flags + threadIdx.x * 16, __ATOMIC_RELAXED, AGENT) < target)
        __builtin_amdgcn_s_sleep(2);
    __syncthreads();
}
__device__ __forceinline__ void gbar(unsigned* flags, unsigned target, int blk) {
    gbar_arrive(flags, target, blk);
    gbar_wait(flags, target);
}

__device__ __forceinline__ void zero4(float4_ (&a)[4]) {
    float4_ z;
    z[0] = 0.f; z[1] = 0.f; z[2] = 0.f; z[3] = 0.f;
#pragma unroll
    for (int i = 0; i < 4; i++) a[i] = z;
}
__device__ __forceinline__ void copy4(float4_ (&d)[4], const float4_ (&s)[4]) {
#pragma unroll
    for (int i = 0; i < 4; i++) d[i] = s[i];
}

// ---- pipelined chunked staging, plain cached loads ----
#define LD2P(dst, base, OFF) \
    asm volatile("global_load_dwordx2 %0, %1, off offset:" #OFF \
                 : "=v"(dst) : "v"(base))

// 8 chunk-base pointers for one A matrix (chunked [256ch][64b][4u] bf16)
#define BASES8(P, A) \
    const char* P##0 = (const char*)(A) + q * 32768 + (lane >> 4) * 1024 + (lane & 15) * 8; \
    const char* P##1 = P##0 + 4096;  const char* P##2 = P##0 + 8192; \
    const char* P##3 = P##0 + 12288; const char* P##4 = P##0 + 16384; \
    const char* P##5 = P##0 + 20480; const char* P##6 = P##0 + 24576; \
    const char* P##7 = P##0 + 28672;

// 16 loads = one batch-tile (mt): 8 s-blocks x {lo,hi} chunk halves.
#define ISSUE16P(LO, HI, LD, P, O0, O1) \
    do { LD(LO[0], P##0, O0); LD(LO[1], P##1, O0); LD(LO[2], P##2, O0); \
         LD(LO[3], P##3, O0); LD(LO[4], P##4, O0); LD(LO[5], P##5, O0); \
         LD(LO[6], P##6, O0); LD(LO[7], P##7, O0); \
         LD(HI[0], P##0, O1); LD(HI[1], P##1, O1); LD(HI[2], P##2, O1); \
         LD(HI[3], P##3, O1); LD(HI[4], P##4, O1); LD(HI[5], P##5, O1); \
         LD(HI[6], P##6, O1); LD(HI[7], P##7, O1); } while (0)

#define WAITV16(N, LO, HI) \
    asm volatile("s_waitcnt vmcnt(" #N ")" \
                 : "+v"(LO[0]), "+v"(LO[1]), "+v"(LO[2]), "+v"(LO[3]), \
                   "+v"(LO[4]), "+v"(LO[5]), "+v"(LO[6]), "+v"(LO[7]), \
                   "+v"(HI[0]), "+v"(HI[1]), "+v"(HI[2]), "+v"(HI[3]), \
                   "+v"(HI[4]), "+v"(HI[5]), "+v"(HI[6]), "+v"(HI[7]))

#define MFMA8C(LO, HI, BF, ACCI) \
    do { _Pragma("unroll") \
         for (int s_ = 0; s_ < 8; s_++) { \
             u64x2 t_; t_[0] = LO[s_]; t_[1] = HI[s_]; \
             ACCI = __builtin_amdgcn_mfma_f32_16x16x32_bf16( \
                 __builtin_bit_cast(short8, t_), BF[s_], ACCI, 0, 0, 0); } } while (0)

// Dual-B: the shared A-fragment feeds two accumulators (separate outputs).
#define MFMA8C2(LO, HI, B1, B2, A1, A2) \
    do { _Pragma("unroll") \
         for (int s_ = 0; s_ < 8; s_++) { \
             u64x2 t_; t_[0] = LO[s_]; t_[1] = HI[s_]; \
             short8 f_ = __builtin_bit_cast(short8, t_); \
             A1 = __builtin_amdgcn_mfma_f32_16x16x32_bf16(f_, B1[s_], A1, 0, 0, 0); \
             A2 = __builtin_amdgcn_mfma_f32_16x16x32_bf16(f_, B2[s_], A2, 0, 0, 0); } } while (0)

// A chunked [256 chunks][64 b][4 u] bf16. A-frag: m = lane&15 (+16*mt),
// k = q*256 + (lane>>4)*8 + s*32 + j. Chunk pair for (s): bases[s], +512.
// 2-deep rotating 16-load batches, partial vmcnt(16); ends WAITV16(0).
__device__ __forceinline__ void mm_pipe(const unsigned short* __restrict__ A,
                                        int q, int lane,
                                        const short8 (&bf)[8], float4_ (&acc)[4]) {
    BASES8(p_, A)
    u64 loA[8], hiA[8], loB[8], hiB[8];
    ISSUE16P(loA, hiA, LD2P, p_, 0, 512);
    ISSUE16P(loB, hiB, LD2P, p_, 128, 640);
    WAITV16(16, loA, hiA); MFMA8C(loA, hiA, bf, acc[0]);
    ISSUE16P(loA, hiA, LD2P, p_, 256, 768);
    WAITV16(16, loB, hiB); MFMA8C(loB, hiB, bf, acc[1]);
    ISSUE16P(loB, hiB, LD2P, p_, 384, 896);
    WAITV16(16, loA, hiA); MFMA8C(loA, hiA, bf, acc[2]);
    WAITV16(0, loB, hiB);  MFMA8C(loB, hiB, bf, acc[3]);
}

// Dual-B variant: one A read, two B sets, two accumulator sets.
__device__ __forceinline__ void mm_pipe_d(const unsigned short* __restrict__ A,
                                          int q, int lane,
                                          const short8 (&b1)[8], const short8 (&b2)[8],
                                          float4_ (&a1)[4], float4_ (&a2)[4]) {
    BASES8(p_, A)
    u64 loA[8], hiA[8], loB[8], hiB[8];
    ISSUE16P(loA, hiA, LD2P, p_, 0, 512);
    ISSUE16P(loB, hiB, LD2P, p_, 128, 640);
    WAITV16(16, loA, hiA); MFMA8C2(loA, hiA, b1, b2, a1[0], a2[0]);
    ISSUE16P(loA, hiA, LD2P, p_, 256, 768);
    WAITV16(16, loB, hiB); MFMA8C2(loB, hiB, b1, b2, a1[1], a2[1]);
    ISSUE16P(loB, hiB, LD2P, p_, 384, 896);
    WAITV16(16, loA, hiA); MFMA8C2(loA, hiA, b1, b2, a1[2], a2[2]);
    WAITV16(0, loB, hiB);  MFMA8C2(loB, hiB, b1, b2, a1[3], a2[3]);
}

// C[m][n]: n = lane&15, m = quad*4+reg  -> gp[(q*64+row)*17+col]
__device__ __forceinline__ void write_parts(float* gp, int q, int lane, float4_ (&acc)[4]) {
    const int col = lane & 15;
    const int rbase = (lane >> 4) * 4;
#pragma unroll
    for (int mt = 0; mt < 4; mt++)
#pragma unroll
        for (int r = 0; r < 4; r++)
            gp[(q * 64 + mt * 16 + rbase + r) * 17 + col] = acc[mt][r];
}

__device__ __forceinline__ float gsum(const float* gp, int b, int c) {
    return gp[(0 * 64 + b) * 17 + c] + gp[(1 * 64 + b) * 17 + c] +
           gp[(2 * 64 + b) * 17 + c] + gp[(3 * 64 + b) * 17 + c];
}

__device__ __forceinline__ short8 packrow(const float* __restrict__ p) {
    short8 r;
#pragma unroll
    for (int j = 0; j < 8; j++) r[j] = (short)f2bf(p[j]);
    return r;
}

__global__ void __launch_bounds__(256, 1)
lstm_core(const float* __restrict__ x, const float* __restrict__ lastp,
          const float* __restrict__ Wih0, const float* __restrict__ Whh0,
          const float* __restrict__ bih0, const float* __restrict__ bhh0,
          const float* __restrict__ Wih1, const float* __restrict__ Whh1,
          const float* __restrict__ bih1, const float* __restrict__ bhh1,
          const float* __restrict__ W1, const float* __restrict__ b1,
          const float* __restrict__ W2, const float* __restrict__ b2,
          float* __restrict__ out, unsigned char* __restrict__ wsb)
{
    const int tid = threadIdx.x;
    const int blk = blockIdx.x;
    const int lane = tid & 63;
    const int q = tid >> 6;          // wave id = K quarter
    const int eb = tid >> 2;         // epilogue: batch row
    const int eu = tid & 3;          // epilogue: unit-within-block
    const int D_ = blk * 4 + eu;     // global hidden unit / fc dim

    unsigned* bar   = (unsigned*)wsb;            // magic word only (bar+544)
    unsigned* flags = (unsigned*)(wsb + 8192);   // 256 flag words (64B spread)
    unsigned short* h0base = (unsigned short*)gws_static;
    unsigned short* h1base = h0base + (size_t)97 * 65536;
    unsigned short* relub  = h0base + (size_t)194 * 65536;

    auto h0p = [&](int g) -> unsigned short* {
        return h0base + (size_t)(g + 1) * 65536;
    };
    auto h1p = [&](int g) -> unsigned short* {
        return h1base + (size_t)(g + 1) * 65536;
    };

    __shared__ float gparts[4 * 64 * 17];
    __shared__ float xlds[2][64 * 21];
    __shared__ float wih0l[16 * 20];

    // ---- barrier area init (block 0): zero flags, then magic ----
    if (blk == 0) {
        __hip_atomic_store(flags + tid * 16, 0u, __ATOMIC_RELAXED, AGENT);
        __syncthreads();
        if (tid == 0)
            __hip_atomic_store(bar + 544, 0x1357BDFu, __ATOMIC_RELEASE, AGENT);
    }

    // ---- prologue: stage x[0] into xlds[0] ----
    for (int i = tid; i < 1280; i += 256) {
        const int bb = i / 20, mm = i - bb * 20;
        xlds[0][bb * 21 + mm] = x[bb * 1280 + mm];
    }

    // ---- per-lane B-fragment preload (bf16, RNE) ----
    const int n_ = lane & 15;
    const int gq_ = n_ >> 2, uu_ = n_ & 3;
    const int growL = gq_ * 1024 + blk * 4 + uu_;   // gate row for this col
    const int kq = (q << 8) + ((lane >> 4) << 3);

    short8 whh0f[8], wih1f[8], whh1f[8], wfusedf[8], wfcf[8];
#pragma unroll
    for (int s = 0; s < 8; s++) {
        const int k = kq + s * 32;
        whh0f[s] = packrow(Whh0 + growL * 1024 + k);
        wih1f[s] = packrow(Wih1 + growL * 1024 + k);
        whh1f[s] = packrow(Whh1 + growL * 1024 + k);
        { // Wfused[row][k] = sum_m Wih0[row][m] * W2[m][k]
            float a8[8] = {0.f, 0.f, 0.f, 0.f, 0.f, 0.f, 0.f, 0.f};
            for (int m = 0; m < 20; m++) {
                float wv = Wih0[growL * 20 + m];
                const float* w2p = W2 + m * 1024 + k;
#pragma unroll
                for (int j = 0; j < 8; j++) a8[j] += wv * w2p[j];
            }
            short8 r;
#pragma unroll
            for (int j = 0; j < 8; j++) r[j] = (short)f2bf(a8[j]);
            wfusedf[s] = r;
        }
        { // fc B: cols 0-3 = W1h rows, cols 4-7 = Wskip rows, 8-15 = 0
            short8 r;
            if (n_ < 4) {
                r = packrow(W1 + (blk * 4 + n_) * 1040 + k);
            } else if (n_ < 8) {
                const int D = blk * 4 + (n_ - 4);
                float a8[8] = {0.f, 0.f, 0.f, 0.f, 0.f, 0.f, 0.f, 0.f};
                for (int g2 = 0; g2 < 16; g2++) {
                    const int m = 5 * (g2 >> 2) + (g2 & 3);
                    float wv = W1[D * 1040 + 1024 + g2] * 0.01f;
                    const float* w2p = W2 + m * 1024 + k;
#pragma unroll
                    for (int j = 0; j < 8; j++) a8[j] += wv * w2p[j];
                }
#pragma unroll
                for (int j = 0; j < 8; j++) r[j] = (short)f2bf(a8[j]);
            } else {
#pragma unroll
                for (int j = 0; j < 8; j++) r[j] = 0;
            }
            wfcf[s] = r;
        }
    }

    // ---- per-thread constants (epilogue mapping: eb = tid>>2, eu = tid&3) ----
    float bias0g[4], bias1g[4], cgv[4];
#pragma unroll
    for (int g = 0; g < 4; g++) {
        const int row = g * 1024 + D_;
        bias0g[g] = bih0[row] + bhh0[row];
        bias1g[g] = bih1[row] + bhh1[row];
        float s = 0.f;
        for (int m = 0; m < 20; m++) s += Wih0[row * 20 + m] * b2[m];
        cgv[g] = s;
    }
    const float fcb = b1[D_];
    float cbv = 0.f, ustate = 0.f;
    for (int g2 = 0; g2 < 16; g2++) {
        const float w1v = W1[D_ * 1040 + 1024 + g2];
        cbv += b2[5 * (g2 >> 2) + (g2 & 3)] * w1v * 0.01f;
        ustate += lastp[eb * 16 + g2] * w1v;   // u(0) = lp0 @ W1lp^T
    }
    float c0v = 0.f, c1v = 0.f;

    if (tid < 16) { // Wih0 rows for x-path (fp32, exact)
        const int row = (tid >> 2) * 1024 + blk * 4 + (tid & 3);
        for (int m = 0; m < 20; m++) wih0l[tid * 20 + m] = Wih0[row * 20 + m];
    }
    // zero initial h state (g = -1); chunked: chunk blk, batch tid
    if (tid < 64) {
        st8_coh(h0p(-1) + blk * 256 + tid * 4, 0ull);
        st8_coh(h1p(-1) + blk * 256 + tid * 4, 0ull);
    }

    if (tid == 0) {
        while (__hip_atomic_load(bar + 544, __ATOMIC_RELAXED, AGENT) != 0x1357BDFu)
            __builtin_amdgcn_s_sleep(2);
    }
    __syncthreads();
    unsigned tgt = 1;
    gbar(flags, tgt, blk); tgt++;

    // ---- direct per-thread publish: thread's element = chunk blk, idx tid ----
    auto publish = [&](unsigned short* dst, unsigned short val) {
        st2_coh(dst + blk * 256 + tid, val);
    };

    auto l0_finish = [&](float4_ (&acc)[4], unsigned short* h0dst, int xt, int pf) {
        write_parts(gparts, q, lane, acc);
        __syncthreads();
        if (pf >= 0) {
            for (int i = tid; i < 1280; i += 256) {
                const int bb = i / 20, mm = i - bb * 20;
                xlds[pf & 1][bb * 21 + mm] = x[bb * 1280 + pf * 20 + mm];
            }
        }
        float gv[4];
#pragma unroll
        for (int g = 0; g < 4; g++) gv[g] = gsum(gparts, eb, g * 4 + eu) + bias0g[g];
        if (xt >= 0) {
#pragma unroll
            for (int g = 0; g < 4; g++) {
                float s = 0.f;
                const float* wr = &wih0l[(g * 4 + eu) * 20];
                const float* xr = &xlds[xt & 1][eb * 21];
                for (int m = 0; m < 20; m++) s += xr[m] * wr[m];
                gv[g] += s;
            }
        } else {
#pragma unroll
            for (int g = 0; g < 4; g++) gv[g] += cgv[g];
        }
        const float iv = sigm(gv[0]), fv = sigm(gv[1]);
        const float gt = tanhf_(gv[2]), ov = sigm(gv[3]);
        c0v = fv * c0v + iv * gt;
        publish(h0dst, f2bf(ov * tanhf_(c0v)));
    };

    auto l1_finish = [&](float4_ (&acc)[4], unsigned short* h1dst) {
        write_parts(gparts, q, lane, acc);
        __syncthreads();
        float gv[4];
#pragma unroll
        for (int g = 0; g < 4; g++) gv[g] = gsum(gparts, eb, g * 4 + eu) + bias1g[g];
        const float iv = sigm(gv[0]), fv = sigm(gv[1]);
        const float gt = tanhf_(gv[2]), ov = sigm(gv[3]);
        c1v = fv * c1v + iv * gt;
        publish(h1dst, f2bf(ov * tanhf_(c1v)));
    };

    auto fc_finish = [&](int t, float4_ (&acc1)[4], float4_ (&acc2)[4]) {
        const int col = lane & 15;
        const int rbase = (lane >> 4) * 4;
        if (col < 8) {
#pragma unroll
            for (int mt = 0; mt < 4; mt++)
#pragma unroll
                for (int r = 0; r < 4; r++) {
                    const float v = (col < 4) ? acc1[mt][r] : acc2[mt][r];
                    gparts[(q * 64 + mt * 16 + rbase + r) * 17 + col] = v;
                }
        }
        __syncthreads();
        const float s1 = gsum(gparts, eb, eu);
        if (t > 0) ustate += gsum(gparts, eb, 4 + eu) + cbv;
        const float rv = fmaxf(s1 + ustate + fcb, 0.f);
        publish(relub + t * 65536, f2bf(rv));
    };

    // carried accumulators
    float4_ haccL0[4];   // whh0 @ h0(g) for the NEXT L0 (from L1's dual)
    float4_ haccSkip[4]; // Wskip @ relu(t-1) for FC (from L0's dual)
    float4_ haccL1[4];   // whh1 @ h1(g-1) (decoder: computed in L0bar window)
    zero4(haccL0);       // whh0 @ h0(-1) == 0 exactly (zero initial state)

    // ---- encoder: 64 steps x {L0(epilogue-only), barrier, L1(dual+mm)} ----
    for (int g = 0; g < 64; g++) {
        float4_ acc[4];
        copy4(acc, haccL0);                       // whh0 @ h0(g-1)
        l0_finish(acc, h0p(g), g, (g < 63) ? g + 1 : -1);
        gbar(flags, tgt, blk); tgt++;
        float4_ accn[4];
        zero4(accn); zero4(haccL0);
        mm_pipe_d(h0p(g), q, lane, wih1f, whh0f, accn, haccL0); // one h0 read
        mm_pipe(h1p(g - 1), q, lane, whh1f, accn);              // wih1 then whh1 (enc order)
        l1_finish(accn, h1p(g));
    }

    // ---- decoder: 32 steps x {L0, b(+whh1 window), L1, b, FC, b} ----
    for (int t = 0; t < 32; t++) {
        const int g = 64 + t;
        unsigned short* rp = (t > 0) ? (relub + (t - 1) * 65536) : nullptr;

        // L0 slot: acc = whh0@h0(g-1) (carried) + wfused@relu (dual w/ Wskip)
        float4_ acc[4];
        copy4(acc, haccL0);
        zero4(haccSkip);
        if (rp) mm_pipe_d(rp, q, lane, wfusedf, wfcf, acc, haccSkip);
        l0_finish(acc, h0p(g), (t == 0) ? 63 : -1, -1);
        gbar_arrive(flags, tgt, blk);
        // WINDOW: whh1 @ h1(g-1). Safe for t>=1: h1(g-1) drained at
        // arrive(L1bar(t-1)); we passed wait(FCbar(t-1)) => all drained.
        // t==0: h1(63) is 0-barriers-old -> done in-phase below.
        zero4(haccL1);
        if (t >= 1) mm_pipe(h1p(g - 1), q, lane, whh1f, haccL1);
        gbar_wait(flags, tgt); tgt++;

        // L1 slot: accn = whh1@h1(g-1) (window/in-phase) then dual h0(g).
        // Decoder L1 order: whh1-then-wih1 (uniform all t).
        float4_ accn[4];
        copy4(accn, haccL1);
        if (t == 0) mm_pipe(h1p(g - 1), q, lane, whh1f, accn); // post-wait: safe
        zero4(haccL0);
        mm_pipe_d(h0p(g), q, lane, wih1f, whh0f, accn, haccL0);
        l1_finish(accn, h1p(g));
        gbar(flags, tgt, blk); tgt++;

        // FC slot: acc1 = W1h@h1 (cols 0-3 valid); acc2 = carried Wskip@relu
        float4_ acc1[4];
        zero4(acc1);
        mm_pipe(h1p(g), q, lane, wfcf, acc1);
        fc_finish(t, acc1, haccSkip);
        gbar(flags, tgt, blk); tgt++;
    }

    // ---- final: pred[t] = relu[t] @ W2^T + b2 -> out[b][t][m] ----
    {
        const int pj = tid >> 5;   // 8 (t,b) pairs per block
        const int m = tid & 31;
        if (m < 20) {
            const int pidx = blk * 8 + pj;
            const int tt = pidx >> 6, bb = pidx & 63;
            const unsigned short* rr = relub + tt * 65536;  // chunked region
            const float* w = W2 + m * 1024;
            float acc = 0.f;
            for (int c = 0; c < 256; c++) {
                const u64 v8 = *(const u64*)(rr + c * 256 + bb * 4);
#pragma unroll
                for (int j = 0; j < 4; j++)
                    acc += bf2f((unsigned short)(v8 >> (16 * j))) * w[c * 4 + j];
            }
            out[bb * 640 + tt * 20 + m] = acc + b2[m];
        }
    }
}

extern "C" void kernel_launch(void* const* d_in, const int* in_sizes, int n_in,
                              void* d_out, int out_size, void* d_ws, size_t ws_size,
                              hipStream_t stream) {
    (void)in_sizes; (void)n_in; (void)out_size; (void)ws_size;
    const float* x     = (const float*)d_in[0];
    const float* lastp = (const float*)d_in[1];
    const float* Wih0  = (const float*)d_in[2];
    const float* Whh0  = (const float*)d_in[3];
    const float* bih0  = (const float*)d_in[4];
    const float* bhh0  = (const float*)d_in[5];
    const float* Wih1  = (const float*)d_in[6];
    const float* Whh1  = (const float*)d_in[7];
    const float* bih1  = (const float*)d_in[8];
    const float* bhh1  = (const float*)d_in[9];
    const float* W1    = (const float*)d_in[10];
    const float* b1    = (const float*)d_in[11];
    const float* W2    = (const float*)d_in[12];
    const float* b2    = (const float*)d_in[13];
    float* out = (float*)d_out;
    unsigned char* ws = (unsigned char*)d_ws;

    void* args[] = {&x, &lastp, &Wih0, &Whh0, &bih0, &bhh0, &Wih1, &Whh1,
                    &bih1, &bhh1, &W1, &b1, &W2, &b2, &out, &ws};
    hipError_t err = hipLaunchCooperativeKernel((const void*)lstm_core,
                                                dim3(256), dim3(256), args, 0, stream);
    if (err != hipSuccess) {
        hipLaunchKernelGGL(lstm_core, dim3(256), dim3(256), 0, stream,
                           x, lastp, Wih0, Whh0, bih0, bhh0, Wih1, Whh1,
                           bih1, bhh1, W1, b1, W2, b2, out, ws);
    }
}